// Round 1
// baseline (5683.686 us; speedup 1.0000x reference)
//
#include <hip/hip_runtime.h>

#define NDEPTH 12
#define NDIM 768
#define NHEADS 12
#define HD 64
#define NB 2
#define NSEQ 2048
#define MTOK (NB*NSEQ)  // 4096

typedef short bf16x8 __attribute__((ext_vector_type(8)));
typedef float f32x4 __attribute__((ext_vector_type(4)));
typedef unsigned short u16;
typedef unsigned int u32;

__device__ inline u16 f2bf(float f){
  union { float f; u32 u; } x; x.f = f;
  u32 r = x.u + 0x7fffu + ((x.u >> 16) & 1u);
  return (u16)(r >> 16);
}

__device__ inline f32x4 mfma16(bf16x8 a, bf16x8 b, f32x4 c){
  return __builtin_amdgcn_mfma_f32_16x16x32_bf16(a, b, c, 0, 0, 0);
}

// ---------------- LayerNorm: one wave per row of 768, out bf16 ----------------
__global__ __launch_bounds__(256) void ln_kernel(const float* __restrict__ x,
    const float* __restrict__ w, const float* __restrict__ b,
    u16* __restrict__ out){
  int wv = threadIdx.x >> 6, lane = threadIdx.x & 63;
  int row = blockIdx.x * 4 + wv;
  const float* xr = x + (size_t)row * NDIM;
  float v[12];
  #pragma unroll
  for (int j = 0; j < 12; j++) v[j] = xr[lane + 64*j];
  float s = 0.f;
  #pragma unroll
  for (int j = 0; j < 12; j++) s += v[j];
  #pragma unroll
  for (int m = 1; m < 64; m <<= 1) s += __shfl_xor(s, m);
  float mean = s * (1.0f/768.0f);
  float q = 0.f;
  #pragma unroll
  for (int j = 0; j < 12; j++){ float d = v[j]-mean; q += d*d; }
  #pragma unroll
  for (int m = 1; m < 64; m <<= 1) q += __shfl_xor(q, m);
  float rs = rsqrtf(q * (1.0f/768.0f) + 1e-5f);
  u16* orow = out + (size_t)row * NDIM;
  #pragma unroll
  for (int j = 0; j < 12; j++){
    int c = lane + 64*j;
    orow[c] = f2bf((v[j]-mean)*rs*w[c] + b[c]);
  }
}

// ---------------- GEMM: C = epi(A[M,K]bf16 * W[K,N]f32->bf16 + bias) ----------------
// EPI 0: out bf16 plain; 1: out bf16 gelu(exact); 2: xres += v * g[col]
template<int EPI>
__global__ __launch_bounds__(256) void gemm_kernel(
    const u16* __restrict__ A, const float* __restrict__ W,
    const float* __restrict__ bias, const float* __restrict__ g,
    u16* __restrict__ outb, float* __restrict__ xres,
    int M, int N, int K)
{
  __shared__ u16 As[128][40];
  __shared__ u16 Bs[128][40];  // transposed: Bs[n][k]
  int nt = N >> 7;
  int bm = blockIdx.x / nt, bn = blockIdx.x % nt;
  int m0 = bm << 7, n0 = bn << 7;
  int t = threadIdx.x, lane = t & 63, wv = t >> 6;
  int wm = (wv >> 1) << 6, wn = (wv & 1) << 6;
  f32x4 acc[4][4] = {};
  int ar = t >> 1, ac = (t & 1) << 4;
  int bk = t >> 3, bnc = (t & 7) << 4;
  int fr = lane & 15, fg8 = (lane >> 4) << 3;

  for (int k0 = 0; k0 < K; k0 += 32){
    __syncthreads();
    // stage A tile [128][32]
    const u16* ap = A + (size_t)(m0 + ar) * K + k0 + ac;
    *(uint4*)&As[ar][ac]     = *(const uint4*)ap;
    *(uint4*)&As[ar][ac + 8] = *(const uint4*)(ap + 8);
    // stage B tile transposed [128 n][32 k], f32 -> bf16
    const float* wp = W + (size_t)(k0 + bk) * N + n0 + bnc;
    #pragma unroll
    for (int i = 0; i < 16; i += 4){
      float4 f = *(const float4*)(wp + i);
      Bs[bnc+i+0][bk] = f2bf(f.x);
      Bs[bnc+i+1][bk] = f2bf(f.y);
      Bs[bnc+i+2][bk] = f2bf(f.z);
      Bs[bnc+i+3][bk] = f2bf(f.w);
    }
    __syncthreads();
    bf16x8 af[4], bfv[4];
    #pragma unroll
    for (int i = 0; i < 4; i++) af[i]  = *(const bf16x8*)&As[wm + i*16 + fr][fg8];
    #pragma unroll
    for (int i = 0; i < 4; i++) bfv[i] = *(const bf16x8*)&Bs[wn + i*16 + fr][fg8];
    #pragma unroll
    for (int mi = 0; mi < 4; mi++)
      #pragma unroll
      for (int ni = 0; ni < 4; ni++)
        acc[mi][ni] = mfma16(af[mi], bfv[ni], acc[mi][ni]);
  }

  int fq = (lane >> 4) << 2;
  #pragma unroll
  for (int mi = 0; mi < 4; mi++){
    #pragma unroll
    for (int ni = 0; ni < 4; ni++){
      int col = n0 + wn + ni*16 + fr;
      float bv = bias[col];
      #pragma unroll
      for (int r = 0; r < 4; r++){
        int row = m0 + wm + mi*16 + fq + r;
        float v = acc[mi][ni][r] + bv;
        if (EPI == 0){
          outb[(size_t)row * N + col] = f2bf(v);
        } else if (EPI == 1){
          float ge = 0.5f * v * (1.0f + erff(v * 0.70710678118f));
          outb[(size_t)row * N + col] = f2bf(ge);
        } else {
          xres[(size_t)row * N + col] += v * g[col];
        }
      }
    }
  }
}

// ---------------- Fused masked flash attention ----------------
// qkv: bf16 [4096][2304] (q | k | v each 768). out: bf16 [4096][768]
__global__ __launch_bounds__(256) void attn_kernel(
    const u16* __restrict__ qkv, const int* __restrict__ sid,
    const unsigned char* __restrict__ smask, u16* __restrict__ outb)
{
  __shared__ u16 Ks[64][72];
  __shared__ u16 Vs[64][72];      // transposed: Vs[d][kk]
  __shared__ u16 Ps[4][16][72];   // per-wave P tiles
  int blk = blockIdx.x;
  int qt = blk & 31; int bh = blk >> 5;
  int b = bh / NHEADS, h = bh % NHEADS;
  int t = threadIdx.x, lane = t & 63, wv = t >> 6;
  int q0 = qt << 6;
  size_t rowbase = (size_t)b * NSEQ;
  int fr = lane & 15, fg8 = (lane >> 4) << 3, fq = (lane >> 4) << 2;

  // Q fragments (held across whole loop)
  int qrow = q0 + (wv << 4) + fr;
  const u16* qp = qkv + (rowbase + qrow) * 2304 + h*64 + fg8;
  bf16x8 qf0 = *(const bf16x8*)qp;
  bf16x8 qf1 = *(const bf16x8*)(qp + 32);

  int sq[4]; int mq[4];
  #pragma unroll
  for (int r = 0; r < 4; r++){
    int qr = q0 + (wv << 4) + fq + r;
    sq[r] = sid[rowbase + qr];
    mq[r] = smask[rowbase + qr];
  }
  float m[4], l[4]; f32x4 o[4] = {};
  #pragma unroll
  for (int r = 0; r < 4; r++){ m[r] = -3.0e38f; l[r] = 0.f; }

  int skk = t >> 2, sd = (t & 3) << 4;

  for (int kt = 0; kt < NSEQ/64; kt++){
    __syncthreads();
    // stage K [64][64] and V^T [64 d][64 kk]
    int krow = (kt << 6) + skk;
    const u16* kp = qkv + (rowbase + krow) * 2304 + 768 + h*64 + sd;
    *(uint4*)&Ks[skk][sd]     = *(const uint4*)kp;
    *(uint4*)&Ks[skk][sd + 8] = *(const uint4*)(kp + 8);
    const u16* vp = kp + 768;
    uint4 v0 = *(const uint4*)vp, v1 = *(const uint4*)(vp + 8);
    {
      const u16* vv = (const u16*)&v0;
      #pragma unroll
      for (int i = 0; i < 8; i++) Vs[sd + i][skk] = vv[i];
      vv = (const u16*)&v1;
      #pragma unroll
      for (int i = 0; i < 8; i++) Vs[sd + 8 + i][skk] = vv[i];
    }
    int ks[4]; int mk[4];
    #pragma unroll
    for (int s2 = 0; s2 < 4; s2++){
      int kk = (kt << 6) + (s2 << 4) + fr;
      ks[s2] = sid[rowbase + kk];
      mk[s2] = smask[rowbase + kk];
    }
    __syncthreads();

    // S = (Q K^T) * scale, masked
    f32x4 S[4];
    #pragma unroll
    for (int s2 = 0; s2 < 4; s2++){
      bf16x8 kf0 = *(const bf16x8*)&Ks[(s2 << 4) + fr][fg8];
      bf16x8 kf1 = *(const bf16x8*)&Ks[(s2 << 4) + fr][fg8 + 32];
      f32x4 s = {};
      s = mfma16(qf0, kf0, s);
      s = mfma16(qf1, kf1, s);
      #pragma unroll
      for (int r = 0; r < 4; r++){
        float v = s[r] * 0.125f;
        bool msk = (mq[r] | mk[s2]) || (sq[r] != ks[s2]);
        S[s2][r] = msk ? -3.0e38f : v;
      }
    }
    // online softmax
    float mn[4], sf[4], rs[4];
    #pragma unroll
    for (int r = 0; r < 4; r++){
      float mx = fmaxf(fmaxf(S[0][r], S[1][r]), fmaxf(S[2][r], S[3][r]));
      #pragma unroll
      for (int d = 1; d < 16; d <<= 1) mx = fmaxf(mx, __shfl_xor(mx, d));
      mn[r] = fmaxf(m[r], mx);
      sf[r] = expf(m[r] - mn[r]);
      rs[r] = 0.f;
    }
    #pragma unroll
    for (int s2 = 0; s2 < 4; s2++){
      #pragma unroll
      for (int r = 0; r < 4; r++){
        float p = expf(S[s2][r] - mn[r]);
        rs[r] += p;
        Ps[wv][fq + r][(s2 << 4) + fr] = f2bf(p);
      }
    }
    #pragma unroll
    for (int r = 0; r < 4; r++){
      #pragma unroll
      for (int d = 1; d < 16; d <<= 1) rs[r] += __shfl_xor(rs[r], d);
      l[r] = l[r] * sf[r] + rs[r];
      m[r] = mn[r];
    }
    #pragma unroll
    for (int dsub = 0; dsub < 4; dsub++)
      #pragma unroll
      for (int r = 0; r < 4; r++) o[dsub][r] *= sf[r];
    __syncthreads();
    // O += P V
    #pragma unroll
    for (int kg = 0; kg < 2; kg++){
      bf16x8 pf = *(const bf16x8*)&Ps[wv][fr][(kg << 5) + fg8];
      #pragma unroll
      for (int dsub = 0; dsub < 4; dsub++){
        bf16x8 vf = *(const bf16x8*)&Vs[(dsub << 4) + fr][(kg << 5) + fg8];
        o[dsub] = mfma16(pf, vf, o[dsub]);
      }
    }
  }

  #pragma unroll
  for (int dsub = 0; dsub < 4; dsub++){
    #pragma unroll
    for (int r = 0; r < 4; r++){
      int row = q0 + (wv << 4) + fq + r;
      int col = h*64 + (dsub << 4) + fr;
      outb[(rowbase + row) * NDIM + col] = f2bf(o[dsub][r] / l[r]);
    }
  }
}

extern "C" void kernel_launch(void* const* d_in, const int* in_sizes, int n_in,
                              void* d_out, int out_size, void* d_ws, size_t ws_size,
                              hipStream_t stream) {
  const float* x_in = (const float*)d_in[0];
  const int* sid = (const int*)d_in[1];
  const unsigned char* smask = (const unsigned char*)d_in[2];
  const float* ln1w = (const float*)d_in[3];
  const float* ln1b = (const float*)d_in[4];
  const float* qkvw = (const float*)d_in[5];
  const float* qkvb = (const float*)d_in[6];
  const float* projw = (const float*)d_in[7];
  const float* projb = (const float*)d_in[8];
  const float* ls1 = (const float*)d_in[9];
  const float* ln2w = (const float*)d_in[10];
  const float* ln2b = (const float*)d_in[11];
  const float* fc1w = (const float*)d_in[12];
  const float* fc1b = (const float*)d_in[13];
  const float* fc2w = (const float*)d_in[14];
  const float* fc2b = (const float*)d_in[15];
  const float* ls2 = (const float*)d_in[16];

  float* x = (float*)d_out;
  char* ws = (char*)d_ws;
  u16* hbuf   = (u16*)ws;                                   // 4096*768 bf16
  u16* qkvbuf = (u16*)(ws + (size_t)4096*768*2);            // 4096*2304 bf16
  u16* abuf   = (u16*)(ws + (size_t)4096*768*2 + (size_t)4096*2304*2);
  u16* mbuf   = (u16*)(ws + (size_t)4096*768*2*2 + (size_t)4096*2304*2); // 4096*3072

  hipMemcpyAsync(x, x_in, (size_t)MTOK*NDIM*4, hipMemcpyDeviceToDevice, stream);

  for (int i = 0; i < NDEPTH; i++){
    ln_kernel<<<MTOK/4, 256, 0, stream>>>(x, ln1w + i*NDIM, ln1b + i*NDIM, hbuf);
    gemm_kernel<0><<<(MTOK/128)*(2304/128), 256, 0, stream>>>(
        hbuf, qkvw + (size_t)i*NDIM*2304, qkvb + (size_t)i*2304, nullptr,
        qkvbuf, nullptr, MTOK, 2304, NDIM);
    attn_kernel<<<NB*NHEADS*(NSEQ/64), 256, 0, stream>>>(qkvbuf, sid, smask, abuf);
    gemm_kernel<2><<<(MTOK/128)*(NDIM/128), 256, 0, stream>>>(
        abuf, projw + (size_t)i*NDIM*NDIM, projb + (size_t)i*NDIM, ls1 + (size_t)i*NDIM,
        nullptr, x, MTOK, NDIM, NDIM);
    ln_kernel<<<MTOK/4, 256, 0, stream>>>(x, ln2w + i*NDIM, ln2b + i*NDIM, hbuf);
    gemm_kernel<1><<<(MTOK/128)*(3072/128), 256, 0, stream>>>(
        hbuf, fc1w + (size_t)i*NDIM*3072, fc1b + (size_t)i*3072, nullptr,
        mbuf, nullptr, MTOK, 3072, NDIM);
    gemm_kernel<2><<<(MTOK/128)*(NDIM/128), 256, 0, stream>>>(
        mbuf, fc2w + (size_t)i*3072*NDIM, fc2b + (size_t)i*NDIM, ls2 + (size_t)i*NDIM,
        nullptr, x, MTOK, NDIM, 3072);
  }
}

// Round 3
// 2648.444 us; speedup vs baseline: 2.1460x; 2.1460x over previous
//
#include <hip/hip_runtime.h>

#define NDEPTH 12
#define NDIM 768
#define NHEADS 12
#define NB 2
#define NSEQ 2048
#define MTOK (NB*NSEQ)  // 4096

typedef short bf16x8 __attribute__((ext_vector_type(8)));
typedef float f32x4 __attribute__((ext_vector_type(4)));
typedef unsigned short u16;
typedef unsigned int u32;

#define L2E 1.44269504088896f

__device__ inline u16 f2bf(float f){
  union { float f; u32 u; } x; x.f = f;
  u32 r = x.u + 0x7fffu + ((x.u >> 16) & 1u);
  return (u16)(r >> 16);
}

__device__ inline f32x4 mfma16(bf16x8 a, bf16x8 b, f32x4 c){
  return __builtin_amdgcn_mfma_f32_16x16x32_bf16(a, b, c, 0, 0, 0);
}

#define GLOAD_LDS(gsrc, ldst) __builtin_amdgcn_global_load_lds( \
    (const __attribute__((address_space(1))) u32*)(gsrc), \
    (__attribute__((address_space(3))) u32*)(ldst), 16, 0, 0)

// ---------------- LayerNorm: one wave per row of 768, out bf16 ----------------
__global__ __launch_bounds__(256) void ln_kernel(const float* __restrict__ x,
    const float* __restrict__ w, const float* __restrict__ b,
    u16* __restrict__ out){
  int wv = threadIdx.x >> 6, lane = threadIdx.x & 63;
  int row = blockIdx.x * 4 + wv;
  const float* xr = x + (size_t)row * NDIM;
  float v[12];
  #pragma unroll
  for (int j = 0; j < 12; j++) v[j] = xr[lane + 64*j];
  float s = 0.f;
  #pragma unroll
  for (int j = 0; j < 12; j++) s += v[j];
  #pragma unroll
  for (int m = 1; m < 64; m <<= 1) s += __shfl_xor(s, m);
  float mean = s * (1.0f/768.0f);
  float q = 0.f;
  #pragma unroll
  for (int j = 0; j < 12; j++){ float d = v[j]-mean; q += d*d; }
  #pragma unroll
  for (int m = 1; m < 64; m <<= 1) q += __shfl_xor(q, m);
  float rs = rsqrtf(q * (1.0f/768.0f) + 1e-5f);
  u16* orow = out + (size_t)row * NDIM;
  #pragma unroll
  for (int j = 0; j < 12; j++){
    int c = lane + 64*j;
    orow[c] = f2bf((v[j]-mean)*rs*w[c] + b[c]);
  }
}

// ---------------- Weight transpose+convert: f32 [K][N] -> bf16 [N][K] ----------------
__global__ __launch_bounds__(256) void wtrans_kernel(const float* __restrict__ in,
    u16* __restrict__ out, int K, int N){
  __shared__ float tile[64][65];
  int n0 = blockIdx.x * 64, k0 = blockIdx.y * 64;
  int t = threadIdx.x;
  #pragma unroll
  for (int j = 0; j < 16; j++){
    int idx = t + j*256;
    int r = idx >> 6, c = idx & 63;
    tile[r][c] = in[(size_t)(k0+r)*N + n0 + c];
  }
  __syncthreads();
  #pragma unroll
  for (int j = 0; j < 16; j++){
    int idx = t + j*256;
    int c = idx >> 6, r = idx & 63;
    out[(size_t)(n0+c)*K + k0 + r] = f2bf(tile[r][c]);
  }
}

// ---------------- GEMM: C = epi(A[M,K]bf16 * Wt[N,K]bf16 + bias) ----------------
// BM=128, BK=64, BN template (128 or 64). 4 waves, wave grid 2x2.
// EPI 0: out bf16; 1: out bf16 gelu(exact); 2: xres += v * g[col]
template<int BN, int EPI>
__global__ __launch_bounds__(256) void gemm_kernel(
    const u16* __restrict__ A, const u16* __restrict__ Wt,
    const float* __restrict__ bias, const float* __restrict__ g,
    u16* __restrict__ outb, float* __restrict__ xres,
    int M, int N, int K)
{
  constexpr int WN = BN/2;
  constexpr int NFR = WN/16;
  __shared__ u16 As[128*64];
  __shared__ u16 Bs[BN*64];
  int nt = N / BN;
  int bm = blockIdx.x / nt, bn = blockIdx.x % nt;
  int m0 = bm*128, n0 = bn*BN;
  int t = threadIdx.x, lane = t & 63, wv = t >> 6;
  int wm = (wv >> 1) * 64, wn = (wv & 1) * WN;
  f32x4 acc[4][NFR] = {};
  int fr = lane & 15, fg = lane >> 4;

  for (int k0 = 0; k0 < K; k0 += 64){
    __syncthreads();
    // stage A [128][64] u16 linear, source pre-swizzled (rule #21)
    #pragma unroll
    for (int i = 0; i < 4; i++){
      int off = t*16 + i*4096;
      int row = off >> 7, cb = off & 127;
      const char* src = (const char*)A + ((size_t)(m0+row)*K + k0)*2 + (cb ^ ((row&7)<<4));
      GLOAD_LDS(src, (char*)As + off);
    }
    #pragma unroll
    for (int i = 0; i < BN/32; i++){
      int off = t*16 + i*4096;
      int row = off >> 7, cb = off & 127;
      const char* src = (const char*)Wt + ((size_t)(n0+row)*K + k0)*2 + (cb ^ ((row&7)<<4));
      GLOAD_LDS(src, (char*)Bs + off);
    }
    __syncthreads();   // compiler drains vmcnt before s_barrier

    bf16x8 af[4][2], bfv[NFR][2];
    #pragma unroll
    for (int mi = 0; mi < 4; mi++)
      #pragma unroll
      for (int kh = 0; kh < 2; kh++){
        int row = wm + mi*16 + fr;
        int off = (row*128 + kh*64 + fg*16) ^ ((row&7)<<4);
        af[mi][kh] = *(const bf16x8*)((const char*)As + off);
      }
    #pragma unroll
    for (int ni = 0; ni < NFR; ni++)
      #pragma unroll
      for (int kh = 0; kh < 2; kh++){
        int row = wn + ni*16 + fr;
        int off = (row*128 + kh*64 + fg*16) ^ ((row&7)<<4);
        bfv[ni][kh] = *(const bf16x8*)((const char*)Bs + off);
      }
    #pragma unroll
    for (int mi = 0; mi < 4; mi++)
      #pragma unroll
      for (int ni = 0; ni < NFR; ni++){
        acc[mi][ni] = mfma16(af[mi][0], bfv[ni][0], acc[mi][ni]);
        acc[mi][ni] = mfma16(af[mi][1], bfv[ni][1], acc[mi][ni]);
      }
  }

  int fq = fg << 2;
  #pragma unroll
  for (int mi = 0; mi < 4; mi++){
    #pragma unroll
    for (int ni = 0; ni < NFR; ni++){
      int col = n0 + wn + ni*16 + fr;
      float bv = bias[col];
      #pragma unroll
      for (int r = 0; r < 4; r++){
        int row = m0 + wm + mi*16 + fq + r;
        float v = acc[mi][ni][r] + bv;
        if (EPI == 0){
          outb[(size_t)row * N + col] = f2bf(v);
        } else if (EPI == 1){
          float ge = 0.5f * v * (1.0f + erff(v * 0.70710678118f));
          outb[(size_t)row * N + col] = f2bf(ge);
        } else {
          xres[(size_t)row * N + col] += v * g[col];
        }
      }
    }
  }
}

// ---------------- Fused masked flash attention with segment-skip ----------------
__global__ __launch_bounds__(256) void attn_kernel(
    const u16* __restrict__ qkv, const int* __restrict__ sid,
    const unsigned char* __restrict__ smask, u16* __restrict__ outb)
{
  __shared__ u16 Ks[64][72];
  __shared__ u16 Vs[64][72];      // transposed: Vs[d][kk]
  __shared__ u16 Ps[4][16][72];
  int blk = blockIdx.x;
  int qt = blk & 31; int bh = blk >> 5;
  int b = bh / NHEADS, h = bh % NHEADS;
  int t = threadIdx.x, lane = t & 63, wv = t >> 6;
  int q0 = qt << 6;
  size_t rowbase = (size_t)b * NSEQ;
  int fr = lane & 15, fg8 = (lane >> 4) << 3, fq = (lane >> 4) << 2;

  int qrow = q0 + (wv << 4) + fr;
  const u16* qp = qkv + (rowbase + qrow) * 2304 + h*64 + fg8;
  bf16x8 qf0 = *(const bf16x8*)qp;
  bf16x8 qf1 = *(const bf16x8*)(qp + 32);

  // block-level segment range (ids sorted per row)
  int qlo = sid[rowbase + q0];
  int qhi = sid[rowbase + q0 + 63];

  int sq[4]; int mq[4];
  #pragma unroll
  for (int r = 0; r < 4; r++){
    int qr = q0 + (wv << 4) + fq + r;
    sq[r] = sid[rowbase + qr];
    mq[r] = smask[rowbase + qr];
  }
  float m[4], l[4]; f32x4 o[4] = {};
  #pragma unroll
  for (int r = 0; r < 4; r++){ m[r] = -3.0e38f; l[r] = 0.f; }

  int skk = t >> 2, sd = (t & 3) << 4;

  for (int kt = 0; kt < NSEQ/64; kt++){
    // skip fully-masked K-tiles (segment ranges don't overlap)
    int klo = sid[rowbase + (kt << 6)];
    int khi = sid[rowbase + (kt << 6) + 63];
    if (khi < qlo || klo > qhi) continue;

    __syncthreads();
    int krow = (kt << 6) + skk;
    const u16* kp = qkv + (rowbase + krow) * 2304 + 768 + h*64 + sd;
    *(uint4*)&Ks[skk][sd]     = *(const uint4*)kp;
    *(uint4*)&Ks[skk][sd + 8] = *(const uint4*)(kp + 8);
    const u16* vp = kp + 768;
    uint4 v0 = *(const uint4*)vp, v1 = *(const uint4*)(vp + 8);
    {
      const u16* vv = (const u16*)&v0;
      #pragma unroll
      for (int i = 0; i < 8; i++) Vs[sd + i][skk] = vv[i];
      vv = (const u16*)&v1;
      #pragma unroll
      for (int i = 0; i < 8; i++) Vs[sd + 8 + i][skk] = vv[i];
    }
    int ks[4]; int mk[4];
    #pragma unroll
    for (int s2 = 0; s2 < 4; s2++){
      int kk = (kt << 6) + (s2 << 4) + fr;
      ks[s2] = sid[rowbase + kk];
      mk[s2] = smask[rowbase + kk];
    }
    __syncthreads();

    f32x4 S[4];
    #pragma unroll
    for (int s2 = 0; s2 < 4; s2++){
      bf16x8 kf0 = *(const bf16x8*)&Ks[(s2 << 4) + fr][fg8];
      bf16x8 kf1 = *(const bf16x8*)&Ks[(s2 << 4) + fr][fg8 + 32];
      f32x4 s = {};
      s = mfma16(qf0, kf0, s);
      s = mfma16(qf1, kf1, s);
      #pragma unroll
      for (int r = 0; r < 4; r++){
        float v = s[r] * 0.125f;
        bool msk = (mq[r] | mk[s2]) || (sq[r] != ks[s2]);
        S[s2][r] = msk ? -3.0e38f : v;
      }
    }
    float mn[4], sf[4], rs[4];
    #pragma unroll
    for (int r = 0; r < 4; r++){
      float mx = fmaxf(fmaxf(S[0][r], S[1][r]), fmaxf(S[2][r], S[3][r]));
      #pragma unroll
      for (int d = 1; d < 16; d <<= 1) mx = fmaxf(mx, __shfl_xor(mx, d));
      mn[r] = fmaxf(m[r], mx);
      sf[r] = exp2f((m[r] - mn[r]) * L2E);
      rs[r] = 0.f;
    }
    #pragma unroll
    for (int s2 = 0; s2 < 4; s2++){
      #pragma unroll
      for (int r = 0; r < 4; r++){
        float p = exp2f((S[s2][r] - mn[r]) * L2E);
        rs[r] += p;
        Ps[wv][fq + r][(s2 << 4) + fr] = f2bf(p);
      }
    }
    #pragma unroll
    for (int r = 0; r < 4; r++){
      #pragma unroll
      for (int d = 1; d < 16; d <<= 1) rs[r] += __shfl_xor(rs[r], d);
      l[r] = l[r] * sf[r] + rs[r];
      m[r] = mn[r];
    }
    #pragma unroll
    for (int dsub = 0; dsub < 4; dsub++)
      #pragma unroll
      for (int r = 0; r < 4; r++) o[dsub][r] *= sf[r];
    __syncthreads();
    #pragma unroll
    for (int kg = 0; kg < 2; kg++){
      bf16x8 pf = *(const bf16x8*)&Ps[wv][fr][(kg << 5) + fg8];
      #pragma unroll
      for (int dsub = 0; dsub < 4; dsub++){
        bf16x8 vf = *(const bf16x8*)&Vs[(dsub << 4) + fr][(kg << 5) + fg8];
        o[dsub] = mfma16(pf, vf, o[dsub]);
      }
    }
  }

  #pragma unroll
  for (int dsub = 0; dsub < 4; dsub++){
    #pragma unroll
    for (int r = 0; r < 4; r++){
      int row = q0 + (wv << 4) + fq + r;
      int col = h*64 + (dsub << 4) + fr;
      outb[(rowbase + row) * NDIM + col] = f2bf(o[dsub][r] / l[r]);
    }
  }
}

extern "C" void kernel_launch(void* const* d_in, const int* in_sizes, int n_in,
                              void* d_out, int out_size, void* d_ws, size_t ws_size,
                              hipStream_t stream) {
  const float* x_in = (const float*)d_in[0];
  const int* sid = (const int*)d_in[1];
  const unsigned char* smask = (const unsigned char*)d_in[2];
  const float* ln1w = (const float*)d_in[3];
  const float* ln1b = (const float*)d_in[4];
  const float* qkvw = (const float*)d_in[5];
  const float* qkvb = (const float*)d_in[6];
  const float* projw = (const float*)d_in[7];
  const float* projb = (const float*)d_in[8];
  const float* ls1 = (const float*)d_in[9];
  const float* ln2w = (const float*)d_in[10];
  const float* ln2b = (const float*)d_in[11];
  const float* fc1w = (const float*)d_in[12];
  const float* fc1b = (const float*)d_in[13];
  const float* fc2w = (const float*)d_in[14];
  const float* fc2b = (const float*)d_in[15];
  const float* ls2 = (const float*)d_in[16];

  float* x = (float*)d_out;
  char* ws = (char*)d_ws;
  u16* hbuf   = (u16*)ws;                                     // 4096*768 bf16
  u16* qkvbuf = (u16*)(ws + (size_t)6291456);                 // 4096*2304 bf16
  u16* abuf   = (u16*)(ws + (size_t)25165824);                // 4096*768 bf16
  u16* mbuf   = (u16*)(ws + (size_t)31457280);                // 4096*3072 bf16
  u16* wtbuf  = (u16*)(ws + (size_t)56623104);                // up to 2304*768 bf16

  hipMemcpyAsync(x, x_in, (size_t)MTOK*NDIM*4, hipMemcpyDeviceToDevice, stream);

  for (int i = 0; i < NDEPTH; i++){
    // ---- attn block ----
    ln_kernel<<<MTOK/4, 256, 0, stream>>>(x, ln1w + i*NDIM, ln1b + i*NDIM, hbuf);
    wtrans_kernel<<<dim3(2304/64, 768/64), 256, 0, stream>>>(
        qkvw + (size_t)i*NDIM*2304, wtbuf, NDIM, 2304);
    gemm_kernel<128,0><<<(MTOK/128)*(2304/128), 256, 0, stream>>>(
        hbuf, wtbuf, qkvb + (size_t)i*2304, nullptr, qkvbuf, nullptr, MTOK, 2304, NDIM);
    attn_kernel<<<NB*NHEADS*(NSEQ/64), 256, 0, stream>>>(qkvbuf, sid, smask, abuf);
    wtrans_kernel<<<dim3(768/64, 768/64), 256, 0, stream>>>(
        projw + (size_t)i*NDIM*NDIM, wtbuf, NDIM, NDIM);
    gemm_kernel<64,2><<<(MTOK/128)*(NDIM/64), 256, 0, stream>>>(
        abuf, wtbuf, projb + (size_t)i*NDIM, ls1 + (size_t)i*NDIM,
        nullptr, x, MTOK, NDIM, NDIM);
    // ---- mlp block ----
    ln_kernel<<<MTOK/4, 256, 0, stream>>>(x, ln2w + i*NDIM, ln2b + i*NDIM, hbuf);
    wtrans_kernel<<<dim3(3072/64, 768/64), 256, 0, stream>>>(
        fc1w + (size_t)i*NDIM*3072, wtbuf, NDIM, 3072);
    gemm_kernel<128,1><<<(MTOK/128)*(3072/128), 256, 0, stream>>>(
        hbuf, wtbuf, fc1b + (size_t)i*3072, nullptr, mbuf, nullptr, MTOK, 3072, NDIM);
    wtrans_kernel<<<dim3(768/64, 3072/64), 256, 0, stream>>>(
        fc2w + (size_t)i*3072*NDIM, wtbuf, 3072, NDIM);
    gemm_kernel<64,2><<<(MTOK/128)*(NDIM/64), 256, 0, stream>>>(
        mbuf, wtbuf, fc2b + (size_t)i*NDIM, ls2 + (size_t)i*NDIM,
        nullptr, x, MTOK, NDIM, 3072);
  }
}

// Round 4
// 2340.047 us; speedup vs baseline: 2.4289x; 1.1318x over previous
//
#include <hip/hip_runtime.h>

#define NDEPTH 12
#define NDIM 768
#define NHEADS 12
#define NB 2
#define NSEQ 2048
#define MTOK (NB*NSEQ)  // 4096

typedef short bf16x8 __attribute__((ext_vector_type(8)));
typedef float f32x4 __attribute__((ext_vector_type(4)));
typedef unsigned short u16;
typedef unsigned int u32;

#define L2E 1.44269504088896f

__device__ inline u16 f2bf(float f){
  union { float f; u32 u; } x; x.f = f;
  u32 r = x.u + 0x7fffu + ((x.u >> 16) & 1u);
  return (u16)(r >> 16);
}

__device__ inline f32x4 mfma16(bf16x8 a, bf16x8 b, f32x4 c){
  return __builtin_amdgcn_mfma_f32_16x16x32_bf16(a, b, c, 0, 0, 0);
}

#define GLOAD_LDS(gsrc, ldst) __builtin_amdgcn_global_load_lds( \
    (const __attribute__((address_space(1))) u32*)(gsrc), \
    (__attribute__((address_space(3))) u32*)(ldst), 16, 0, 0)

// ---------------- LayerNorm: one wave per row of 768, out bf16 ----------------
__global__ __launch_bounds__(256) void ln_kernel(const float* __restrict__ x,
    const float* __restrict__ w, const float* __restrict__ b,
    u16* __restrict__ out){
  int wv = threadIdx.x >> 6, lane = threadIdx.x & 63;
  int row = blockIdx.x * 4 + wv;
  const float* xr = x + (size_t)row * NDIM;
  float v[12];
  #pragma unroll
  for (int j = 0; j < 12; j++) v[j] = xr[lane + 64*j];
  float s = 0.f;
  #pragma unroll
  for (int j = 0; j < 12; j++) s += v[j];
  #pragma unroll
  for (int m = 1; m < 64; m <<= 1) s += __shfl_xor(s, m);
  float mean = s * (1.0f/768.0f);
  float q = 0.f;
  #pragma unroll
  for (int j = 0; j < 12; j++){ float d = v[j]-mean; q += d*d; }
  #pragma unroll
  for (int m = 1; m < 64; m <<= 1) q += __shfl_xor(q, m);
  float rs = rsqrtf(q * (1.0f/768.0f) + 1e-5f);
  u16* orow = out + (size_t)row * NDIM;
  #pragma unroll
  for (int j = 0; j < 12; j++){
    int c = lane + 64*j;
    orow[c] = f2bf((v[j]-mean)*rs*w[c] + b[c]);
  }
}

// ---------------- Weight transpose+convert: f32 [K][N] -> bf16 [N][K] ----------------
__device__ inline void wtrans_body(const float* __restrict__ in,
    u16* __restrict__ out, int K, int N, int n0, int k0, float* tile){
  int t = threadIdx.x;
  #pragma unroll
  for (int j = 0; j < 16; j++){
    int idx = t + j*256;
    int r = idx >> 6, c = idx & 63;
    tile[r*65 + c] = in[(size_t)(k0+r)*N + n0 + c];
  }
  __syncthreads();
  #pragma unroll
  for (int j = 0; j < 16; j++){
    int idx = t + j*256;
    int c = idx >> 6, r = idx & 63;
    out[(size_t)(n0+c)*K + k0 + r] = f2bf(tile[r*65 + c]);
  }
}

__global__ __launch_bounds__(256) void wtrans_kernel(const float* __restrict__ in,
    u16* __restrict__ out, int K, int N){
  __shared__ float tile[64*65];
  wtrans_body(in, out, K, N, blockIdx.x*64, blockIdx.y*64, tile);
}

// Fused: all four weights of one layer in a single launch (1728 blocks)
__global__ __launch_bounds__(256) void wtrans4_kernel(
    const float* __restrict__ qkvw, const float* __restrict__ projw,
    const float* __restrict__ fc1w, const float* __restrict__ fc2w,
    u16* __restrict__ wq, u16* __restrict__ wp,
    u16* __restrict__ w1, u16* __restrict__ w2){
  __shared__ float tile[64*65];
  int bid = blockIdx.x;
  const float* in; u16* out; int K, N, tl;
  if (bid < 432){        in = qkvw; out = wq; K = 768;  N = 2304; tl = bid; }
  else if (bid < 576){   in = projw; out = wp; K = 768; N = 768;  tl = bid - 432; }
  else if (bid < 1152){  in = fc1w; out = w1; K = 768;  N = 3072; tl = bid - 576; }
  else {                 in = fc2w; out = w2; K = 3072; N = 768;  tl = bid - 1152; }
  int ntn = N >> 6;
  int n0 = (tl % ntn) << 6, k0 = (tl / ntn) << 6;
  wtrans_body(in, out, K, N, n0, k0, tile);
}

// ---------------- GEMM: C = epi(A[M,K]bf16 * Wt[N,K]bf16 + bias) ----------------
// BM=128, BK=64, 2-phase LDS double-buffer, one barrier per K-step.
// EPI 0: out bf16; 1: out bf16 gelu(exact); 2: xres += v * g[col]
template<int BN, int EPI>
__global__ __launch_bounds__(256) void gemm_kernel(
    const u16* __restrict__ A, const u16* __restrict__ Wt,
    const float* __restrict__ bias, const float* __restrict__ g,
    u16* __restrict__ outb, float* __restrict__ xres,
    int M, int N, int K)
{
  constexpr int WN = BN/2;
  constexpr int NFR = WN/16;
  __shared__ u16 As[2][128*64];
  __shared__ u16 Bs[2][BN*64];
  // XCD-aware bijective swizzle (gridDim.x % 8 == 0 for all our launches)
  int nwg = gridDim.x;
  int bid = (blockIdx.x & 7) * (nwg >> 3) + (blockIdx.x >> 3);
  int nt = N / BN;
  int bm = bid / nt, bn = bid % nt;
  int m0 = bm*128, n0 = bn*BN;
  int t = threadIdx.x, lane = t & 63, wv = t >> 6;
  int wm = (wv >> 1) * 64, wn = (wv & 1) * WN;
  f32x4 acc[4][NFR] = {};
  int fr = lane & 15, fg = lane >> 4;

  auto stage = [&](int bf, int k0){
    #pragma unroll
    for (int i = 0; i < 4; i++){
      int off = t*16 + i*4096;
      int row = off >> 7, cb = off & 127;
      const char* src = (const char*)A + ((size_t)(m0+row)*K + k0)*2 + (cb ^ ((row&7)<<4));
      GLOAD_LDS(src, (char*)As[bf] + off);
    }
    #pragma unroll
    for (int i = 0; i < BN/32; i++){
      int off = t*16 + i*4096;
      int row = off >> 7, cb = off & 127;
      const char* src = (const char*)Wt + ((size_t)(n0+row)*K + k0)*2 + (cb ^ ((row&7)<<4));
      GLOAD_LDS(src, (char*)Bs[bf] + off);
    }
  };

  stage(0, 0);
  int cur = 0;
  for (int k0 = 0; k0 < K; k0 += 64){
    __syncthreads();               // drains vmcnt: buf[cur] ready; all waves done reading buf[cur^1]
    if (k0 + 64 < K) stage(cur ^ 1, k0 + 64);   // prefetch flies under the MFMAs below

    bf16x8 af[4][2], bfv[NFR][2];
    #pragma unroll
    for (int mi = 0; mi < 4; mi++)
      #pragma unroll
      for (int kh = 0; kh < 2; kh++){
        int row = wm + mi*16 + fr;
        int off = (row*128 + kh*64 + fg*16) ^ ((row&7)<<4);
        af[mi][kh] = *(const bf16x8*)((const char*)As[cur] + off);
      }
    #pragma unroll
    for (int ni = 0; ni < NFR; ni++)
      #pragma unroll
      for (int kh = 0; kh < 2; kh++){
        int row = wn + ni*16 + fr;
        int off = (row*128 + kh*64 + fg*16) ^ ((row&7)<<4);
        bfv[ni][kh] = *(const bf16x8*)((const char*)Bs[cur] + off);
      }
    #pragma unroll
    for (int mi = 0; mi < 4; mi++)
      #pragma unroll
      for (int ni = 0; ni < NFR; ni++){
        acc[mi][ni] = mfma16(af[mi][0], bfv[ni][0], acc[mi][ni]);
        acc[mi][ni] = mfma16(af[mi][1], bfv[ni][1], acc[mi][ni]);
      }
    cur ^= 1;
  }

  int fq = fg << 2;
  #pragma unroll
  for (int mi = 0; mi < 4; mi++){
    #pragma unroll
    for (int ni = 0; ni < NFR; ni++){
      int col = n0 + wn + ni*16 + fr;
      float bv = bias[col];
      #pragma unroll
      for (int r = 0; r < 4; r++){
        int row = m0 + wm + mi*16 + fq + r;
        float v = acc[mi][ni][r] + bv;
        if (EPI == 0){
          outb[(size_t)row * N + col] = f2bf(v);
        } else if (EPI == 1){
          float ge = 0.5f * v * (1.0f + erff(v * 0.70710678118f));
          outb[(size_t)row * N + col] = f2bf(ge);
        } else {
          xres[(size_t)row * N + col] += v * g[col];
        }
      }
    }
  }
}

// ---------------- Fused masked flash attention with segment-skip ----------------
__global__ __launch_bounds__(256) void attn_kernel(
    const u16* __restrict__ qkv, const int* __restrict__ sid,
    const unsigned char* __restrict__ smask, u16* __restrict__ outb)
{
  __shared__ u16 Ks[64][72];
  __shared__ u16 Vs[64][72];      // transposed: Vs[d][kk]
  __shared__ u16 Ps[4][16][72];
  // XCD swizzle: 96 consecutive blocks (3 heads) per XCD -> K/V L2 locality
  int nwg = gridDim.x;
  int blk = (blockIdx.x & 7) * (nwg >> 3) + (blockIdx.x >> 3);
  int qt = blk & 31; int bh = blk >> 5;
  int b = bh / NHEADS, h = bh % NHEADS;
  int t = threadIdx.x, lane = t & 63, wv = t >> 6;
  int q0 = qt << 6;
  size_t rowbase = (size_t)b * NSEQ;
  int fr = lane & 15, fg8 = (lane >> 4) << 3, fq = (lane >> 4) << 2;

  int qrow = q0 + (wv << 4) + fr;
  const u16* qp = qkv + (rowbase + qrow) * 2304 + h*64 + fg8;
  bf16x8 qf0 = *(const bf16x8*)qp;
  bf16x8 qf1 = *(const bf16x8*)(qp + 32);

  int qlo = sid[rowbase + q0];
  int qhi = sid[rowbase + q0 + 63];

  int sq[4]; int mq[4];
  #pragma unroll
  for (int r = 0; r < 4; r++){
    int qr = q0 + (wv << 4) + fq + r;
    sq[r] = sid[rowbase + qr];
    mq[r] = smask[rowbase + qr];
  }
  float m[4], l[4]; f32x4 o[4] = {};
  #pragma unroll
  for (int r = 0; r < 4; r++){ m[r] = -3.0e38f; l[r] = 0.f; }

  int skk = t >> 2, sd = (t & 3) << 4;

  for (int kt = 0; kt < NSEQ/64; kt++){
    int klo = sid[rowbase + (kt << 6)];
    int khi = sid[rowbase + (kt << 6) + 63];
    if (khi < qlo || klo > qhi) continue;

    __syncthreads();
    int krow = (kt << 6) + skk;
    const u16* kp = qkv + (rowbase + krow) * 2304 + 768 + h*64 + sd;
    *(uint4*)&Ks[skk][sd]     = *(const uint4*)kp;
    *(uint4*)&Ks[skk][sd + 8] = *(const uint4*)(kp + 8);
    const u16* vp = kp + 768;
    uint4 v0 = *(const uint4*)vp, v1 = *(const uint4*)(vp + 8);
    {
      const u16* vv = (const u16*)&v0;
      #pragma unroll
      for (int i = 0; i < 8; i++) Vs[sd + i][skk] = vv[i];
      vv = (const u16*)&v1;
      #pragma unroll
      for (int i = 0; i < 8; i++) Vs[sd + 8 + i][skk] = vv[i];
    }
    int ks[4]; int mk[4];
    #pragma unroll
    for (int s2 = 0; s2 < 4; s2++){
      int kk = (kt << 6) + (s2 << 4) + fr;
      ks[s2] = sid[rowbase + kk];
      mk[s2] = smask[rowbase + kk];
    }
    __syncthreads();

    f32x4 S[4];
    #pragma unroll
    for (int s2 = 0; s2 < 4; s2++){
      bf16x8 kf0 = *(const bf16x8*)&Ks[(s2 << 4) + fr][fg8];
      bf16x8 kf1 = *(const bf16x8*)&Ks[(s2 << 4) + fr][fg8 + 32];
      f32x4 s = {};
      s = mfma16(qf0, kf0, s);
      s = mfma16(qf1, kf1, s);
      #pragma unroll
      for (int r = 0; r < 4; r++){
        float v = s[r] * 0.125f;
        bool msk = (mq[r] | mk[s2]) || (sq[r] != ks[s2]);
        S[s2][r] = msk ? -3.0e38f : v;
      }
    }
    float mn[4], sf[4], rs[4];
    #pragma unroll
    for (int r = 0; r < 4; r++){
      float mx = fmaxf(fmaxf(S[0][r], S[1][r]), fmaxf(S[2][r], S[3][r]));
      #pragma unroll
      for (int d = 1; d < 16; d <<= 1) mx = fmaxf(mx, __shfl_xor(mx, d));
      mn[r] = fmaxf(m[r], mx);
      sf[r] = exp2f((m[r] - mn[r]) * L2E);
      rs[r] = 0.f;
    }
    #pragma unroll
    for (int s2 = 0; s2 < 4; s2++){
      #pragma unroll
      for (int r = 0; r < 4; r++){
        float p = exp2f((S[s2][r] - mn[r]) * L2E);
        rs[r] += p;
        Ps[wv][fq + r][(s2 << 4) + fr] = f2bf(p);
      }
    }
    #pragma unroll
    for (int r = 0; r < 4; r++){
      #pragma unroll
      for (int d = 1; d < 16; d <<= 1) rs[r] += __shfl_xor(rs[r], d);
      l[r] = l[r] * sf[r] + rs[r];
      m[r] = mn[r];
    }
    #pragma unroll
    for (int dsub = 0; dsub < 4; dsub++)
      #pragma unroll
      for (int r = 0; r < 4; r++) o[dsub][r] *= sf[r];
    __syncthreads();
    #pragma unroll
    for (int kg = 0; kg < 2; kg++){
      bf16x8 pf = *(const bf16x8*)&Ps[wv][fr][(kg << 5) + fg8];
      #pragma unroll
      for (int dsub = 0; dsub < 4; dsub++){
        bf16x8 vf = *(const bf16x8*)&Vs[(dsub << 4) + fr][(kg << 5) + fg8];
        o[dsub] = mfma16(pf, vf, o[dsub]);
      }
    }
  }

  #pragma unroll
  for (int dsub = 0; dsub < 4; dsub++){
    #pragma unroll
    for (int r = 0; r < 4; r++){
      int row = q0 + (wv << 4) + fq + r;
      int col = h*64 + (dsub << 4) + fr;
      outb[(rowbase + row) * NDIM + col] = f2bf(o[dsub][r] / l[r]);
    }
  }
}

extern "C" void kernel_launch(void* const* d_in, const int* in_sizes, int n_in,
                              void* d_out, int out_size, void* d_ws, size_t ws_size,
                              hipStream_t stream) {
  const float* x_in = (const float*)d_in[0];
  const int* sid = (const int*)d_in[1];
  const unsigned char* smask = (const unsigned char*)d_in[2];
  const float* ln1w = (const float*)d_in[3];
  const float* ln1b = (const float*)d_in[4];
  const float* qkvw = (const float*)d_in[5];
  const float* qkvb = (const float*)d_in[6];
  const float* projw = (const float*)d_in[7];
  const float* projb = (const float*)d_in[8];
  const float* ls1 = (const float*)d_in[9];
  const float* ln2w = (const float*)d_in[10];
  const float* ln2b = (const float*)d_in[11];
  const float* fc1w = (const float*)d_in[12];
  const float* fc1b = (const float*)d_in[13];
  const float* fc2w = (const float*)d_in[14];
  const float* fc2b = (const float*)d_in[15];
  const float* ls2 = (const float*)d_in[16];

  float* x = (float*)d_out;
  char* ws = (char*)d_ws;
  u16* hbuf   = (u16*)ws;                                     // 4096*768 bf16
  u16* qkvbuf = (u16*)(ws + (size_t)6291456);                 // 4096*2304 bf16
  u16* abuf   = (u16*)(ws + (size_t)25165824);                // 4096*768 bf16
  u16* mbuf   = (u16*)(ws + (size_t)31457280);                // 4096*3072 bf16
  const size_t WT0 = 56623104;

  bool fused_wt = ws_size >= (size_t)(WT0 + 14155776);
  u16* wq; u16* wp; u16* w1; u16* w2;
  if (fused_wt){
    wq = (u16*)(ws + WT0);
    wp = wq + (size_t)2304*768;
    w1 = wp + (size_t)768*768;
    w2 = w1 + (size_t)768*3072;
  } else {
    wq = wp = w1 = w2 = (u16*)(ws + WT0);
  }

  hipMemcpyAsync(x, x_in, (size_t)MTOK*NDIM*4, hipMemcpyDeviceToDevice, stream);

  for (int i = 0; i < NDEPTH; i++){
    const float* qw = qkvw + (size_t)i*NDIM*2304;
    const float* pw = projw + (size_t)i*NDIM*NDIM;
    const float* f1 = fc1w + (size_t)i*NDIM*3072;
    const float* f2 = fc2w + (size_t)i*3072*NDIM;

    if (fused_wt){
      wtrans4_kernel<<<1728, 256, 0, stream>>>(qw, pw, f1, f2, wq, wp, w1, w2);
    }
    // ---- attn block ----
    ln_kernel<<<MTOK/4, 256, 0, stream>>>(x, ln1w + i*NDIM, ln1b + i*NDIM, hbuf);
    if (!fused_wt)
      wtrans_kernel<<<dim3(2304/64, 768/64), 256, 0, stream>>>(qw, wq, NDIM, 2304);
    gemm_kernel<128,0><<<(MTOK/128)*(2304/128), 256, 0, stream>>>(
        hbuf, wq, qkvb + (size_t)i*2304, nullptr, qkvbuf, nullptr, MTOK, 2304, NDIM);
    attn_kernel<<<NB*NHEADS*(NSEQ/64), 256, 0, stream>>>(qkvbuf, sid, smask, abuf);
    if (!fused_wt)
      wtrans_kernel<<<dim3(768/64, 768/64), 256, 0, stream>>>(pw, wp, NDIM, NDIM);
    gemm_kernel<64,2><<<(MTOK/128)*(NDIM/64), 256, 0, stream>>>(
        abuf, wp, projb + (size_t)i*NDIM, ls1 + (size_t)i*NDIM,
        nullptr, x, MTOK, NDIM, NDIM);
    // ---- mlp block ----
    ln_kernel<<<MTOK/4, 256, 0, stream>>>(x, ln2w + i*NDIM, ln2b + i*NDIM, hbuf);
    if (!fused_wt)
      wtrans_kernel<<<dim3(3072/64, 768/64), 256, 0, stream>>>(f1, w1, NDIM, 3072);
    gemm_kernel<128,1><<<(MTOK/128)*(3072/128), 256, 0, stream>>>(
        hbuf, w1, fc1b + (size_t)i*3072, nullptr, mbuf, nullptr, MTOK, 3072, NDIM);
    if (!fused_wt)
      wtrans_kernel<<<dim3(768/64, 3072/64), 256, 0, stream>>>(f2, w2, 3072, NDIM);
    gemm_kernel<64,2><<<(MTOK/128)*(NDIM/64), 256, 0, stream>>>(
        mbuf, w2, fc2b + (size_t)i*NDIM, ls2 + (size_t)i*NDIM,
        nullptr, x, MTOK, NDIM, 3072);
  }
}

// Round 5
// 2201.853 us; speedup vs baseline: 2.5813x; 1.0628x over previous
//
#include <hip/hip_runtime.h>

#define NDEPTH 12
#define NDIM 768
#define NHEADS 12
#define NB 2
#define NSEQ 2048
#define MTOK (NB*NSEQ)  // 4096

typedef short bf16x8 __attribute__((ext_vector_type(8)));
typedef float f32x4 __attribute__((ext_vector_type(4)));
typedef unsigned short u16;
typedef unsigned int u32;

#define L2E 1.44269504088896f

__device__ inline u16 f2bf(float f){
  union { float f; u32 u; } x; x.f = f;
  u32 r = x.u + 0x7fffu + ((x.u >> 16) & 1u);
  return (u16)(r >> 16);
}

__device__ inline f32x4 mfma16(bf16x8 a, bf16x8 b, f32x4 c){
  return __builtin_amdgcn_mfma_f32_16x16x32_bf16(a, b, c, 0, 0, 0);
}

#define GLOAD_LDS(gsrc, ldst) __builtin_amdgcn_global_load_lds( \
    (const __attribute__((address_space(1))) u32*)(gsrc), \
    (__attribute__((address_space(3))) u32*)(ldst), 16, 0, 0)

// ---------------- LayerNorm body: one wave per row of 768, out bf16 ----------------
__device__ inline void ln_body(const float* __restrict__ x,
    const float* __restrict__ w, const float* __restrict__ b,
    u16* __restrict__ out, int blk){
  int wv = threadIdx.x >> 6, lane = threadIdx.x & 63;
  int row = blk * 4 + wv;
  const float* xr = x + (size_t)row * NDIM;
  float v[12];
  #pragma unroll
  for (int j = 0; j < 12; j++) v[j] = xr[lane + 64*j];
  float s = 0.f;
  #pragma unroll
  for (int j = 0; j < 12; j++) s += v[j];
  #pragma unroll
  for (int m = 1; m < 64; m <<= 1) s += __shfl_xor(s, m);
  float mean = s * (1.0f/768.0f);
  float q = 0.f;
  #pragma unroll
  for (int j = 0; j < 12; j++){ float d = v[j]-mean; q += d*d; }
  #pragma unroll
  for (int m = 1; m < 64; m <<= 1) q += __shfl_xor(q, m);
  float rs = rsqrtf(q * (1.0f/768.0f) + 1e-5f);
  u16* orow = out + (size_t)row * NDIM;
  #pragma unroll
  for (int j = 0; j < 12; j++){
    int c = lane + 64*j;
    orow[c] = f2bf((v[j]-mean)*rs*w[c] + b[c]);
  }
}

__global__ __launch_bounds__(256) void ln_kernel(const float* __restrict__ x,
    const float* __restrict__ w, const float* __restrict__ b,
    u16* __restrict__ out){
  ln_body(x, w, b, out, blockIdx.x);
}

// ---------------- Weight transpose+convert: f32 [K][N] -> bf16 [N][K] ----------------
__device__ inline void wtrans_body(const float* __restrict__ in,
    u16* __restrict__ out, int K, int N, int n0, int k0, float* tile){
  int t = threadIdx.x;
  #pragma unroll
  for (int j = 0; j < 16; j++){
    int idx = t + j*256;
    int r = idx >> 6, c = idx & 63;
    tile[r*65 + c] = in[(size_t)(k0+r)*N + n0 + c];
  }
  __syncthreads();
  #pragma unroll
  for (int j = 0; j < 16; j++){
    int idx = t + j*256;
    int c = idx >> 6, r = idx & 63;
    out[(size_t)(n0+c)*K + k0 + r] = f2bf(tile[r*65 + c]);
  }
}

__global__ __launch_bounds__(256) void wtrans_kernel(const float* __restrict__ in,
    u16* __restrict__ out, int K, int N){
  __shared__ float tile[64*65];
  wtrans_body(in, out, K, N, blockIdx.x*64, blockIdx.y*64, tile);
}

// Fused: ln1 (blocks 0..1023) + all four weight transposes (1024..2751)
__global__ __launch_bounds__(256) void lnwt_kernel(
    const float* __restrict__ x, const float* __restrict__ lw,
    const float* __restrict__ lb, u16* __restrict__ lout,
    const float* __restrict__ qkvw, const float* __restrict__ projw,
    const float* __restrict__ fc1w, const float* __restrict__ fc2w,
    u16* __restrict__ wq, u16* __restrict__ wp,
    u16* __restrict__ w1, u16* __restrict__ w2){
  __shared__ float tile[64*65];
  int bid = blockIdx.x;
  if (bid < 1024){ ln_body(x, lw, lb, lout, bid); return; }
  bid -= 1024;
  const float* in; u16* out; int K, N, tl;
  if (bid < 432){        in = qkvw; out = wq; K = 768;  N = 2304; tl = bid; }
  else if (bid < 576){   in = projw; out = wp; K = 768; N = 768;  tl = bid - 432; }
  else if (bid < 1152){  in = fc1w; out = w1; K = 768;  N = 3072; tl = bid - 576; }
  else {                 in = fc2w; out = w2; K = 3072; N = 768;  tl = bid - 1152; }
  int ntn = N >> 6;
  int n0 = (tl % ntn) << 6, k0 = (tl / ntn) << 6;
  wtrans_body(in, out, K, N, n0, k0, tile);
}

// ---------------- GEMM: C = epi(A[M,K]bf16 * Wt[N,K]bf16 + bias) ----------------
// BM=128, BK=32, 8 waves (512 thr), 2-phase LDS dbuf, one barrier per K-step.
// EPI 0: out bf16; 1: out bf16 gelu(exact); 2: xres += v * g[col]
template<int BN, int EPI>
__global__ __launch_bounds__(512) void gemm_kernel(
    const u16* __restrict__ A, const u16* __restrict__ Wt,
    const float* __restrict__ bias, const float* __restrict__ g,
    u16* __restrict__ outb, float* __restrict__ xres,
    int M, int N, int K)
{
  constexpr int WGM = (BN == 128) ? 2 : 4;   // wave-grid rows
  constexpr int WGN = 8 / WGM;               // wave-grid cols
  constexpr int WTM = 128 / WGM;             // 64 or 32
  constexpr int WTN = BN / WGN;              // 32
  constexpr int MI = WTM / 16;               // 4 or 2
  constexpr int NI = WTN / 16;               // 2
  __shared__ u16 As[2][128*32];
  __shared__ u16 Bs[2][BN*32];
  // XCD-aware bijective swizzle (gridDim.x % 8 == 0 for all our launches)
  int nwg = gridDim.x;
  int bid = (blockIdx.x & 7) * (nwg >> 3) + (blockIdx.x >> 3);
  int nt = N / BN;
  int bm = bid / nt, bn = bid % nt;
  int m0 = bm*128, n0 = bn*BN;
  int t = threadIdx.x, lane = t & 63, wv = t >> 6;
  int wm = (wv / WGN) * WTM, wn = (wv % WGN) * WTN;
  f32x4 acc[MI][NI] = {};
  int fr = lane & 15, fg = lane >> 4;

  auto stage = [&](int bf, int k0){
    {
      int off = t*16;                 // 0..8191 covers [128][32] u16
      int row = off >> 6, cb = off & 63;
      const char* src = (const char*)A + ((size_t)(m0+row)*K + k0)*2 + (cb ^ ((row&3)<<4));
      GLOAD_LDS(src, (char*)As[bf] + off);
    }
    if (BN == 128 || t < 256){
      int off = t*16;                 // Bs is BN*64 bytes
      int row = off >> 6, cb = off & 63;
      const char* src = (const char*)Wt + ((size_t)(n0+row)*K + k0)*2 + (cb ^ ((row&3)<<4));
      GLOAD_LDS(src, (char*)Bs[bf] + off);
    }
  };

  stage(0, 0);
  int cur = 0;
  for (int k0 = 0; k0 < K; k0 += 32){
    __syncthreads();               // buf[cur] ready; all waves done with buf[cur^1]
    if (k0 + 32 < K) stage(cur ^ 1, k0 + 32);   // prefetch flies under MFMAs

    bf16x8 af[MI], bfv[NI];
    #pragma unroll
    for (int mi = 0; mi < MI; mi++){
      int row = wm + mi*16 + fr;
      int off = (row*64 + fg*16) ^ ((row&3)<<4);
      af[mi] = *(const bf16x8*)((const char*)As[cur] + off);
    }
    #pragma unroll
    for (int ni = 0; ni < NI; ni++){
      int row = wn + ni*16 + fr;
      int off = (row*64 + fg*16) ^ ((row&3)<<4);
      bfv[ni] = *(const bf16x8*)((const char*)Bs[cur] + off);
    }
    #pragma unroll
    for (int mi = 0; mi < MI; mi++)
      #pragma unroll
      for (int ni = 0; ni < NI; ni++)
        acc[mi][ni] = mfma16(af[mi], bfv[ni], acc[mi][ni]);
    cur ^= 1;
  }

  int fq = fg << 2;
  #pragma unroll
  for (int mi = 0; mi < MI; mi++){
    #pragma unroll
    for (int ni = 0; ni < NI; ni++){
      int col = n0 + wn + ni*16 + fr;
      float bv = bias[col];
      #pragma unroll
      for (int r = 0; r < 4; r++){
        int row = m0 + wm + mi*16 + fq + r;
        float v = acc[mi][ni][r] + bv;
        if (EPI == 0){
          outb[(size_t)row * N + col] = f2bf(v);
        } else if (EPI == 1){
          float ge = 0.5f * v * (1.0f + erff(v * 0.70710678118f));
          outb[(size_t)row * N + col] = f2bf(ge);
        } else {
          xres[(size_t)row * N + col] += v * g[col];
        }
      }
    }
  }
}

// ---------------- Fused masked flash attention with segment-skip ----------------
__global__ __launch_bounds__(256) void attn_kernel(
    const u16* __restrict__ qkv, const int* __restrict__ sid,
    const unsigned char* __restrict__ smask, u16* __restrict__ outb)
{
  __shared__ u16 Ks[64][72];
  __shared__ u16 Vs[64][72];      // transposed: Vs[d][kk]
  __shared__ u16 Ps[4][16][72];
  int nwg = gridDim.x;
  int blk = (blockIdx.x & 7) * (nwg >> 3) + (blockIdx.x >> 3);
  int qt = blk & 31; int bh = blk >> 5;
  int b = bh / NHEADS, h = bh % NHEADS;
  int t = threadIdx.x, lane = t & 63, wv = t >> 6;
  int q0 = qt << 6;
  size_t rowbase = (size_t)b * NSEQ;
  int fr = lane & 15, fg8 = (lane >> 4) << 3, fq = (lane >> 4) << 2;

  int qrow = q0 + (wv << 4) + fr;
  const u16* qp = qkv + (rowbase + qrow) * 2304 + h*64 + fg8;
  bf16x8 qf0 = *(const bf16x8*)qp;
  bf16x8 qf1 = *(const bf16x8*)(qp + 32);

  int qlo = sid[rowbase + q0];
  int qhi = sid[rowbase + q0 + 63];

  int sq[4]; int mq[4];
  #pragma unroll
  for (int r = 0; r < 4; r++){
    int qr = q0 + (wv << 4) + fq + r;
    sq[r] = sid[rowbase + qr];
    mq[r] = smask[rowbase + qr];
  }
  float m[4], l[4]; f32x4 o[4] = {};
  #pragma unroll
  for (int r = 0; r < 4; r++){ m[r] = -3.0e38f; l[r] = 0.f; }

  int skk = t >> 2, sd = (t & 3) << 4;

  for (int kt = 0; kt < NSEQ/64; kt++){
    int klo = sid[rowbase + (kt << 6)];
    int khi = sid[rowbase + (kt << 6) + 63];
    if (khi < qlo || klo > qhi) continue;

    __syncthreads();
    int krow = (kt << 6) + skk;
    const u16* kp = qkv + (rowbase + krow) * 2304 + 768 + h*64 + sd;
    *(uint4*)&Ks[skk][sd]     = *(const uint4*)kp;
    *(uint4*)&Ks[skk][sd + 8] = *(const uint4*)(kp + 8);
    const u16* vp = kp + 768;
    uint4 v0 = *(const uint4*)vp, v1 = *(const uint4*)(vp + 8);
    {
      const u16* vv = (const u16*)&v0;
      #pragma unroll
      for (int i = 0; i < 8; i++) Vs[sd + i][skk] = vv[i];
      vv = (const u16*)&v1;
      #pragma unroll
      for (int i = 0; i < 8; i++) Vs[sd + 8 + i][skk] = vv[i];
    }
    int ks[4]; int mk[4];
    #pragma unroll
    for (int s2 = 0; s2 < 4; s2++){
      int kk = (kt << 6) + (s2 << 4) + fr;
      ks[s2] = sid[rowbase + kk];
      mk[s2] = smask[rowbase + kk];
    }
    __syncthreads();

    f32x4 S[4];
    #pragma unroll
    for (int s2 = 0; s2 < 4; s2++){
      bf16x8 kf0 = *(const bf16x8*)&Ks[(s2 << 4) + fr][fg8];
      bf16x8 kf1 = *(const bf16x8*)&Ks[(s2 << 4) + fr][fg8 + 32];
      f32x4 s = {};
      s = mfma16(qf0, kf0, s);
      s = mfma16(qf1, kf1, s);
      #pragma unroll
      for (int r = 0; r < 4; r++){
        float v = s[r] * 0.125f;
        bool msk = (mq[r] | mk[s2]) || (sq[r] != ks[s2]);
        S[s2][r] = msk ? -3.0e38f : v;
      }
    }
    float mn[4], sf[4], rs[4];
    #pragma unroll
    for (int r = 0; r < 4; r++){
      float mx = fmaxf(fmaxf(S[0][r], S[1][r]), fmaxf(S[2][r], S[3][r]));
      #pragma unroll
      for (int d = 1; d < 16; d <<= 1) mx = fmaxf(mx, __shfl_xor(mx, d));
      mn[r] = fmaxf(m[r], mx);
      sf[r] = exp2f((m[r] - mn[r]) * L2E);
      rs[r] = 0.f;
    }
    #pragma unroll
    for (int s2 = 0; s2 < 4; s2++){
      #pragma unroll
      for (int r = 0; r < 4; r++){
        float p = exp2f((S[s2][r] - mn[r]) * L2E);
        rs[r] += p;
        Ps[wv][fq + r][(s2 << 4) + fr] = f2bf(p);
      }
    }
    #pragma unroll
    for (int r = 0; r < 4; r++){
      #pragma unroll
      for (int d = 1; d < 16; d <<= 1) rs[r] += __shfl_xor(rs[r], d);
      l[r] = l[r] * sf[r] + rs[r];
      m[r] = mn[r];
    }
    #pragma unroll
    for (int dsub = 0; dsub < 4; dsub++)
      #pragma unroll
      for (int r = 0; r < 4; r++) o[dsub][r] *= sf[r];
    __syncthreads();
    #pragma unroll
    for (int kg = 0; kg < 2; kg++){
      bf16x8 pf = *(const bf16x8*)&Ps[wv][fr][(kg << 5) + fg8];
      #pragma unroll
      for (int dsub = 0; dsub < 4; dsub++){
        bf16x8 vf = *(const bf16x8*)&Vs[(dsub << 4) + fr][(kg << 5) + fg8];
        o[dsub] = mfma16(pf, vf, o[dsub]);
      }
    }
  }

  #pragma unroll
  for (int dsub = 0; dsub < 4; dsub++){
    #pragma unroll
    for (int r = 0; r < 4; r++){
      int row = q0 + (wv << 4) + fq + r;
      int col = h*64 + (dsub << 4) + fr;
      outb[(rowbase + row) * NDIM + col] = f2bf(o[dsub][r] / l[r]);
    }
  }
}

extern "C" void kernel_launch(void* const* d_in, const int* in_sizes, int n_in,
                              void* d_out, int out_size, void* d_ws, size_t ws_size,
                              hipStream_t stream) {
  const float* x_in = (const float*)d_in[0];
  const int* sid = (const int*)d_in[1];
  const unsigned char* smask = (const unsigned char*)d_in[2];
  const float* ln1w = (const float*)d_in[3];
  const float* ln1b = (const float*)d_in[4];
  const float* qkvw = (const float*)d_in[5];
  const float* qkvb = (const float*)d_in[6];
  const float* projw = (const float*)d_in[7];
  const float* projb = (const float*)d_in[8];
  const float* ls1 = (const float*)d_in[9];
  const float* ln2w = (const float*)d_in[10];
  const float* ln2b = (const float*)d_in[11];
  const float* fc1w = (const float*)d_in[12];
  const float* fc1b = (const float*)d_in[13];
  const float* fc2w = (const float*)d_in[14];
  const float* fc2b = (const float*)d_in[15];
  const float* ls2 = (const float*)d_in[16];

  float* x = (float*)d_out;
  char* ws = (char*)d_ws;
  u16* hbuf   = (u16*)ws;                                     // 4096*768 bf16
  u16* qkvbuf = (u16*)(ws + (size_t)6291456);                 // 4096*2304 bf16
  u16* abuf   = (u16*)(ws + (size_t)25165824);                // 4096*768 bf16
  u16* mbuf   = (u16*)(ws + (size_t)31457280);                // 4096*3072 bf16
  const size_t WT0 = 56623104;

  bool fused_wt = ws_size >= (size_t)(WT0 + 14155776);
  u16* wq; u16* wp; u16* w1; u16* w2;
  if (fused_wt){
    wq = (u16*)(ws + WT0);
    wp = wq + (size_t)2304*768;
    w1 = wp + (size_t)768*768;
    w2 = w1 + (size_t)768*3072;
  } else {
    wq = wp = w1 = w2 = (u16*)(ws + WT0);
  }

  hipMemcpyAsync(x, x_in, (size_t)MTOK*NDIM*4, hipMemcpyDeviceToDevice, stream);

  for (int i = 0; i < NDEPTH; i++){
    const float* qw = qkvw + (size_t)i*NDIM*2304;
    const float* pw = projw + (size_t)i*NDIM*NDIM;
    const float* f1 = fc1w + (size_t)i*NDIM*3072;
    const float* f2 = fc2w + (size_t)i*3072*NDIM;

    // ---- attn block ----
    if (fused_wt){
      lnwt_kernel<<<2752, 256, 0, stream>>>(x, ln1w + i*NDIM, ln1b + i*NDIM, hbuf,
                                            qw, pw, f1, f2, wq, wp, w1, w2);
    } else {
      ln_kernel<<<MTOK/4, 256, 0, stream>>>(x, ln1w + i*NDIM, ln1b + i*NDIM, hbuf);
      wtrans_kernel<<<dim3(2304/64, 768/64), 256, 0, stream>>>(qw, wq, NDIM, 2304);
    }
    gemm_kernel<128,0><<<(MTOK/128)*(2304/128), 512, 0, stream>>>(
        hbuf, wq, qkvb + (size_t)i*2304, nullptr, qkvbuf, nullptr, MTOK, 2304, NDIM);
    attn_kernel<<<NB*NHEADS*(NSEQ/64), 256, 0, stream>>>(qkvbuf, sid, smask, abuf);
    if (!fused_wt)
      wtrans_kernel<<<dim3(768/64, 768/64), 256, 0, stream>>>(pw, wp, NDIM, NDIM);
    gemm_kernel<64,2><<<(MTOK/128)*(NDIM/64), 512, 0, stream>>>(
        abuf, wp, projb + (size_t)i*NDIM, ls1 + (size_t)i*NDIM,
        nullptr, x, MTOK, NDIM, NDIM);
    // ---- mlp block ----
    ln_kernel<<<MTOK/4, 256, 0, stream>>>(x, ln2w + i*NDIM, ln2b + i*NDIM, hbuf);
    if (!fused_wt)
      wtrans_kernel<<<dim3(3072/64, 768/64), 256, 0, stream>>>(f1, w1, NDIM, 3072);
    gemm_kernel<128,1><<<(MTOK/128)*(3072/128), 512, 0, stream>>>(
        hbuf, w1, fc1b + (size_t)i*3072, nullptr, mbuf, nullptr, MTOK, 3072, NDIM);
    if (!fused_wt)
      wtrans_kernel<<<dim3(768/64, 3072/64), 256, 0, stream>>>(f2, w2, 3072, NDIM);
    gemm_kernel<64,2><<<(MTOK/128)*(NDIM/64), 512, 0, stream>>>(
        mbuf, w2, fc2b + (size_t)i*NDIM, ls2 + (size_t)i*NDIM,
        nullptr, x, MTOK, NDIM, 3072);
  }
}

// Round 6
// 2078.779 us; speedup vs baseline: 2.7341x; 1.0592x over previous
//
#include <hip/hip_runtime.h>

#define NDEPTH 12
#define NDIM 768
#define NHEADS 12
#define NB 2
#define NSEQ 2048
#define MTOK (NB*NSEQ)  // 4096

typedef short bf16x8 __attribute__((ext_vector_type(8)));
typedef float f32x4 __attribute__((ext_vector_type(4)));
typedef unsigned short u16;
typedef unsigned int u32;

#define L2E 1.44269504088896f

__device__ inline u16 f2bf(float f){
  union { float f; u32 u; } x; x.f = f;
  u32 r = x.u + 0x7fffu + ((x.u >> 16) & 1u);
  return (u16)(r >> 16);
}

__device__ inline f32x4 mfma16(bf16x8 a, bf16x8 b, f32x4 c){
  return __builtin_amdgcn_mfma_f32_16x16x32_bf16(a, b, c, 0, 0, 0);
}

#define GLOAD_LDS(gsrc, ldst) __builtin_amdgcn_global_load_lds( \
    (const __attribute__((address_space(1))) u32*)(gsrc), \
    (__attribute__((address_space(3))) u32*)(ldst), 16, 0, 0)

// ---------------- LayerNorm body: one wave per row of 768, out bf16 ----------------
__device__ inline void ln_body(const float* __restrict__ x,
    const float* __restrict__ w, const float* __restrict__ b,
    u16* __restrict__ out, int blk){
  int wv = threadIdx.x >> 6, lane = threadIdx.x & 63;
  int row = blk * 4 + wv;
  const float* xr = x + (size_t)row * NDIM;
  float v[12];
  #pragma unroll
  for (int j = 0; j < 12; j++) v[j] = xr[lane + 64*j];
  float s = 0.f;
  #pragma unroll
  for (int j = 0; j < 12; j++) s += v[j];
  #pragma unroll
  for (int m = 1; m < 64; m <<= 1) s += __shfl_xor(s, m);
  float mean = s * (1.0f/768.0f);
  float q = 0.f;
  #pragma unroll
  for (int j = 0; j < 12; j++){ float d = v[j]-mean; q += d*d; }
  #pragma unroll
  for (int m = 1; m < 64; m <<= 1) q += __shfl_xor(q, m);
  float rs = rsqrtf(q * (1.0f/768.0f) + 1e-5f);
  u16* orow = out + (size_t)row * NDIM;
  #pragma unroll
  for (int j = 0; j < 12; j++){
    int c = lane + 64*j;
    orow[c] = f2bf((v[j]-mean)*rs*w[c] + b[c]);
  }
}

__global__ __launch_bounds__(256) void ln_kernel(const float* __restrict__ x,
    const float* __restrict__ w, const float* __restrict__ b,
    u16* __restrict__ out){
  ln_body(x, w, b, out, blockIdx.x);
}

// ---------------- Weight transpose+convert: f32 [K][N] -> bf16 [N][K] ----------------
__device__ inline void wtrans_body(const float* __restrict__ in,
    u16* __restrict__ out, int K, int N, int n0, int k0, float* tile){
  int t = threadIdx.x;
  #pragma unroll
  for (int j = 0; j < 16; j++){
    int idx = t + j*256;
    int r = idx >> 6, c = idx & 63;
    tile[r*65 + c] = in[(size_t)(k0+r)*N + n0 + c];
  }
  __syncthreads();
  #pragma unroll
  for (int j = 0; j < 16; j++){
    int idx = t + j*256;
    int c = idx >> 6, r = idx & 63;
    out[(size_t)(n0+c)*K + k0 + r] = f2bf(tile[r*65 + c]);
  }
}

__global__ __launch_bounds__(256) void wtrans_kernel(const float* __restrict__ in,
    u16* __restrict__ out, int K, int N){
  __shared__ float tile[64*65];
  wtrans_body(in, out, K, N, blockIdx.x*64, blockIdx.y*64, tile);
}

// Fused: ln1 (blocks 0..1023) + all four weight transposes (1024..2751)
__global__ __launch_bounds__(256) void lnwt_kernel(
    const float* __restrict__ x, const float* __restrict__ lw,
    const float* __restrict__ lb, u16* __restrict__ lout,
    const float* __restrict__ qkvw, const float* __restrict__ projw,
    const float* __restrict__ fc1w, const float* __restrict__ fc2w,
    u16* __restrict__ wq, u16* __restrict__ wp,
    u16* __restrict__ w1, u16* __restrict__ w2){
  __shared__ float tile[64*65];
  int bid = blockIdx.x;
  if (bid < 1024){ ln_body(x, lw, lb, lout, bid); return; }
  bid -= 1024;
  const float* in; u16* out; int K, N, tl;
  if (bid < 432){        in = qkvw; out = wq; K = 768;  N = 2304; tl = bid; }
  else if (bid < 576){   in = projw; out = wp; K = 768; N = 768;  tl = bid - 432; }
  else if (bid < 1152){  in = fc1w; out = w1; K = 768;  N = 3072; tl = bid - 576; }
  else {                 in = fc2w; out = w2; K = 3072; N = 768;  tl = bid - 1152; }
  int ntn = N >> 6;
  int n0 = (tl % ntn) << 6, k0 = (tl / ntn) << 6;
  wtrans_body(in, out, K, N, n0, k0, tile);
}

// ---------------- GEMM: C = epi(A[M,K]bf16 * Wt[N,K]bf16 + bias) ----------------
// BM=128, BK=64, 8 waves (512 thr), 2-phase LDS dbuf, one barrier per K-step.
// BN=128: wave grid 2x4 (wave tile 64x32, 16 MFMA/step). BN=64: 4x2 (32x32).
// EPI 0: out bf16; 1: out bf16 gelu(exact); 2: xres += v * g[col]
template<int BN, int EPI>
__global__ __launch_bounds__(512) void gemm_kernel(
    const u16* __restrict__ A, const u16* __restrict__ Wt,
    const float* __restrict__ bias, const float* __restrict__ g,
    u16* __restrict__ outb, float* __restrict__ xres,
    int M, int N, int K)
{
  constexpr int WGN = BN / 32;               // wave-grid cols (4 or 2)
  constexpr int WGM = 8 / WGN;               // wave-grid rows (2 or 4)
  constexpr int WTM = 128 / WGM;             // 64 or 32
  constexpr int MI = WTM / 16;               // 4 or 2
  constexpr int NI = 2;                      // 32/16
  __shared__ u16 As[2][128*64];
  __shared__ u16 Bs[2][BN*64];
  // XCD-aware bijective swizzle (gridDim.x % 8 == 0 for all our launches)
  int nwg = gridDim.x;
  int bid = (blockIdx.x & 7) * (nwg >> 3) + (blockIdx.x >> 3);
  int nt = N / BN;
  int bm = bid / nt, bn = bid % nt;
  int m0 = bm*128, n0 = bn*BN;
  int t = threadIdx.x, lane = t & 63, wv = t >> 6;
  int wm = (wv / WGN) * WTM, wn = (wv % WGN) * 32;
  f32x4 acc[MI][NI] = {};
  int fr = lane & 15, fg = lane >> 4;

  auto stage = [&](int bf, int k0){
    #pragma unroll
    for (int i = 0; i < 2; i++){
      int off = t*16 + i*8192;
      int row = off >> 7, cb = off & 127;
      const char* src = (const char*)A + ((size_t)(m0+row)*K + k0)*2 + (cb ^ ((row&7)<<4));
      GLOAD_LDS(src, (char*)As[bf] + off);
    }
    #pragma unroll
    for (int i = 0; i < BN/64; i++){
      int off = t*16 + i*8192;
      int row = off >> 7, cb = off & 127;
      const char* src = (const char*)Wt + ((size_t)(n0+row)*K + k0)*2 + (cb ^ ((row&7)<<4));
      GLOAD_LDS(src, (char*)Bs[bf] + off);
    }
  };

  stage(0, 0);
  int cur = 0;
  for (int k0 = 0; k0 < K; k0 += 64){
    __syncthreads();               // buf[cur] ready; all waves done with buf[cur^1]
    if (k0 + 64 < K) stage(cur ^ 1, k0 + 64);   // prefetch flies under MFMAs

    bf16x8 af[MI][2], bfv[NI][2];
    #pragma unroll
    for (int mi = 0; mi < MI; mi++)
      #pragma unroll
      for (int kh = 0; kh < 2; kh++){
        int row = wm + mi*16 + fr;
        int off = (row*128 + kh*64 + fg*16) ^ ((row&7)<<4);
        af[mi][kh] = *(const bf16x8*)((const char*)As[cur] + off);
      }
    #pragma unroll
    for (int ni = 0; ni < NI; ni++)
      #pragma unroll
      for (int kh = 0; kh < 2; kh++){
        int row = wn + ni*16 + fr;
        int off = (row*128 + kh*64 + fg*16) ^ ((row&7)<<4);
        bfv[ni][kh] = *(const bf16x8*)((const char*)Bs[cur] + off);
      }
    #pragma unroll
    for (int mi = 0; mi < MI; mi++)
      #pragma unroll
      for (int ni = 0; ni < NI; ni++){
        acc[mi][ni] = mfma16(af[mi][0], bfv[ni][0], acc[mi][ni]);
        acc[mi][ni] = mfma16(af[mi][1], bfv[ni][1], acc[mi][ni]);
      }
    cur ^= 1;
  }

  int fq = fg << 2;
  #pragma unroll
  for (int mi = 0; mi < MI; mi++){
    #pragma unroll
    for (int ni = 0; ni < NI; ni++){
      int col = n0 + wn + ni*16 + fr;
      float bv = bias[col];
      #pragma unroll
      for (int r = 0; r < 4; r++){
        int row = m0 + wm + mi*16 + fq + r;
        float v = acc[mi][ni][r] + bv;
        if (EPI == 0){
          outb[(size_t)row * N + col] = f2bf(v);
        } else if (EPI == 1){
          float ge = 0.5f * v * (1.0f + erff(v * 0.70710678118f));
          outb[(size_t)row * N + col] = f2bf(ge);
        } else {
          xres[(size_t)row * N + col] += v * g[col];
        }
      }
    }
  }
}

// ---------------- Fused masked flash attention with segment-skip ----------------
__global__ __launch_bounds__(256) void attn_kernel(
    const u16* __restrict__ qkv, const int* __restrict__ sid,
    const unsigned char* __restrict__ smask, u16* __restrict__ outb)
{
  __shared__ u16 Ks[64][72];
  __shared__ u16 Vs[64][72];      // transposed: Vs[d][kk]
  __shared__ u16 Ps[4][16][72];
  int nwg = gridDim.x;
  int blk = (blockIdx.x & 7) * (nwg >> 3) + (blockIdx.x >> 3);
  int qt = blk & 31; int bh = blk >> 5;
  int b = bh / NHEADS, h = bh % NHEADS;
  int t = threadIdx.x, lane = t & 63, wv = t >> 6;
  int q0 = qt << 6;
  size_t rowbase = (size_t)b * NSEQ;
  int fr = lane & 15, fg8 = (lane >> 4) << 3, fq = (lane >> 4) << 2;

  int qrow = q0 + (wv << 4) + fr;
  const u16* qp = qkv + (rowbase + qrow) * 2304 + h*64 + fg8;
  bf16x8 qf0 = *(const bf16x8*)qp;
  bf16x8 qf1 = *(const bf16x8*)(qp + 32);

  int qlo = sid[rowbase + q0];
  int qhi = sid[rowbase + q0 + 63];

  int sq[4]; int mq[4];
  #pragma unroll
  for (int r = 0; r < 4; r++){
    int qr = q0 + (wv << 4) + fq + r;
    sq[r] = sid[rowbase + qr];
    mq[r] = smask[rowbase + qr];
  }
  float m[4], l[4]; f32x4 o[4] = {};
  #pragma unroll
  for (int r = 0; r < 4; r++){ m[r] = -3.0e38f; l[r] = 0.f; }

  int skk = t >> 2, sd = (t & 3) << 4;

  for (int kt = 0; kt < NSEQ/64; kt++){
    int klo = sid[rowbase + (kt << 6)];
    int khi = sid[rowbase + (kt << 6) + 63];
    if (khi < qlo || klo > qhi) continue;

    __syncthreads();
    int krow = (kt << 6) + skk;
    const u16* kp = qkv + (rowbase + krow) * 2304 + 768 + h*64 + sd;
    *(uint4*)&Ks[skk][sd]     = *(const uint4*)kp;
    *(uint4*)&Ks[skk][sd + 8] = *(const uint4*)(kp + 8);
    const u16* vp = kp + 768;
    uint4 v0 = *(const uint4*)vp, v1 = *(const uint4*)(vp + 8);
    {
      const u16* vv = (const u16*)&v0;
      #pragma unroll
      for (int i = 0; i < 8; i++) Vs[sd + i][skk] = vv[i];
      vv = (const u16*)&v1;
      #pragma unroll
      for (int i = 0; i < 8; i++) Vs[sd + 8 + i][skk] = vv[i];
    }
    int ks[4]; int mk[4];
    #pragma unroll
    for (int s2 = 0; s2 < 4; s2++){
      int kk = (kt << 6) + (s2 << 4) + fr;
      ks[s2] = sid[rowbase + kk];
      mk[s2] = smask[rowbase + kk];
    }
    __syncthreads();

    f32x4 S[4];
    #pragma unroll
    for (int s2 = 0; s2 < 4; s2++){
      bf16x8 kf0 = *(const bf16x8*)&Ks[(s2 << 4) + fr][fg8];
      bf16x8 kf1 = *(const bf16x8*)&Ks[(s2 << 4) + fr][fg8 + 32];
      f32x4 s = {};
      s = mfma16(qf0, kf0, s);
      s = mfma16(qf1, kf1, s);
      #pragma unroll
      for (int r = 0; r < 4; r++){
        float v = s[r] * 0.125f;
        bool msk = (mq[r] | mk[s2]) || (sq[r] != ks[s2]);
        S[s2][r] = msk ? -3.0e38f : v;
      }
    }
    float mn[4], sf[4], rs[4];
    #pragma unroll
    for (int r = 0; r < 4; r++){
      float mx = fmaxf(fmaxf(S[0][r], S[1][r]), fmaxf(S[2][r], S[3][r]));
      #pragma unroll
      for (int d = 1; d < 16; d <<= 1) mx = fmaxf(mx, __shfl_xor(mx, d));
      mn[r] = fmaxf(m[r], mx);
      sf[r] = exp2f((m[r] - mn[r]) * L2E);
      rs[r] = 0.f;
    }
    #pragma unroll
    for (int s2 = 0; s2 < 4; s2++){
      #pragma unroll
      for (int r = 0; r < 4; r++){
        float p = exp2f((S[s2][r] - mn[r]) * L2E);
        rs[r] += p;
        Ps[wv][fq + r][(s2 << 4) + fr] = f2bf(p);
      }
    }
    #pragma unroll
    for (int r = 0; r < 4; r++){
      #pragma unroll
      for (int d = 1; d < 16; d <<= 1) rs[r] += __shfl_xor(rs[r], d);
      l[r] = l[r] * sf[r] + rs[r];
      m[r] = mn[r];
    }
    #pragma unroll
    for (int dsub = 0; dsub < 4; dsub++)
      #pragma unroll
      for (int r = 0; r < 4; r++) o[dsub][r] *= sf[r];
    __syncthreads();
    #pragma unroll
    for (int kg = 0; kg < 2; kg++){
      bf16x8 pf = *(const bf16x8*)&Ps[wv][fr][(kg << 5) + fg8];
      #pragma unroll
      for (int dsub = 0; dsub < 4; dsub++){
        bf16x8 vf = *(const bf16x8*)&Vs[(dsub << 4) + fr][(kg << 5) + fg8];
        o[dsub] = mfma16(pf, vf, o[dsub]);
      }
    }
  }

  #pragma unroll
  for (int dsub = 0; dsub < 4; dsub++){
    #pragma unroll
    for (int r = 0; r < 4; r++){
      int row = q0 + (wv << 4) + fq + r;
      int col = h*64 + (dsub << 4) + fr;
      outb[(rowbase + row) * NDIM + col] = f2bf(o[dsub][r] / l[r]);
    }
  }
}

extern "C" void kernel_launch(void* const* d_in, const int* in_sizes, int n_in,
                              void* d_out, int out_size, void* d_ws, size_t ws_size,
                              hipStream_t stream) {
  const float* x_in = (const float*)d_in[0];
  const int* sid = (const int*)d_in[1];
  const unsigned char* smask = (const unsigned char*)d_in[2];
  const float* ln1w = (const float*)d_in[3];
  const float* ln1b = (const float*)d_in[4];
  const float* qkvw = (const float*)d_in[5];
  const float* qkvb = (const float*)d_in[6];
  const float* projw = (const float*)d_in[7];
  const float* projb = (const float*)d_in[8];
  const float* ls1 = (const float*)d_in[9];
  const float* ln2w = (const float*)d_in[10];
  const float* ln2b = (const float*)d_in[11];
  const float* fc1w = (const float*)d_in[12];
  const float* fc1b = (const float*)d_in[13];
  const float* fc2w = (const float*)d_in[14];
  const float* fc2b = (const float*)d_in[15];
  const float* ls2 = (const float*)d_in[16];

  float* x = (float*)d_out;
  char* ws = (char*)d_ws;
  u16* hbuf   = (u16*)ws;                                     // 4096*768 bf16
  u16* qkvbuf = (u16*)(ws + (size_t)6291456);                 // 4096*2304 bf16
  u16* abuf   = (u16*)(ws + (size_t)25165824);                // 4096*768 bf16
  u16* mbuf   = (u16*)(ws + (size_t)31457280);                // 4096*3072 bf16
  const size_t WT0 = 56623104;

  bool fused_wt = ws_size >= (size_t)(WT0 + 14155776);
  u16* wq; u16* wp; u16* w1; u16* w2;
  if (fused_wt){
    wq = (u16*)(ws + WT0);
    wp = wq + (size_t)2304*768;
    w1 = wp + (size_t)768*768;
    w2 = w1 + (size_t)768*3072;
  } else {
    wq = wp = w1 = w2 = (u16*)(ws + WT0);
  }

  hipMemcpyAsync(x, x_in, (size_t)MTOK*NDIM*4, hipMemcpyDeviceToDevice, stream);

  for (int i = 0; i < NDEPTH; i++){
    const float* qw = qkvw + (size_t)i*NDIM*2304;
    const float* pw = projw + (size_t)i*NDIM*NDIM;
    const float* f1 = fc1w + (size_t)i*NDIM*3072;
    const float* f2 = fc2w + (size_t)i*3072*NDIM;

    // ---- attn block ----
    if (fused_wt){
      lnwt_kernel<<<2752, 256, 0, stream>>>(x, ln1w + i*NDIM, ln1b + i*NDIM, hbuf,
                                            qw, pw, f1, f2, wq, wp, w1, w2);
    } else {
      ln_kernel<<<MTOK/4, 256, 0, stream>>>(x, ln1w + i*NDIM, ln1b + i*NDIM, hbuf);
      wtrans_kernel<<<dim3(2304/64, 768/64), 256, 0, stream>>>(qw, wq, NDIM, 2304);
    }
    gemm_kernel<128,0><<<(MTOK/128)*(2304/128), 512, 0, stream>>>(
        hbuf, wq, qkvb + (size_t)i*2304, nullptr, qkvbuf, nullptr, MTOK, 2304, NDIM);
    attn_kernel<<<NB*NHEADS*(NSEQ/64), 256, 0, stream>>>(qkvbuf, sid, smask, abuf);
    if (!fused_wt)
      wtrans_kernel<<<dim3(768/64, 768/64), 256, 0, stream>>>(pw, wp, NDIM, NDIM);
    gemm_kernel<64,2><<<(MTOK/128)*(NDIM/64), 512, 0, stream>>>(
        abuf, wp, projb + (size_t)i*NDIM, ls1 + (size_t)i*NDIM,
        nullptr, x, MTOK, NDIM, NDIM);
    // ---- mlp block ----
    ln_kernel<<<MTOK/4, 256, 0, stream>>>(x, ln2w + i*NDIM, ln2b + i*NDIM, hbuf);
    if (!fused_wt)
      wtrans_kernel<<<dim3(3072/64, 768/64), 256, 0, stream>>>(f1, w1, NDIM, 3072);
    gemm_kernel<128,1><<<(MTOK/128)*(3072/128), 512, 0, stream>>>(
        hbuf, w1, fc1b + (size_t)i*3072, nullptr, mbuf, nullptr, MTOK, 3072, NDIM);
    if (!fused_wt)
      wtrans_kernel<<<dim3(768/64, 3072/64), 256, 0, stream>>>(f2, w2, 3072, NDIM);
    gemm_kernel<64,2><<<(MTOK/128)*(NDIM/64), 512, 0, stream>>>(
        mbuf, w2, fc2b + (size_t)i*NDIM, ls2 + (size_t)i*NDIM,
        nullptr, x, MTOK, NDIM, 3072);
  }
}